// Round 3
// baseline (81.500 us; speedup 1.0000x reference)
//
#include <hip/hip_runtime.h>

#define BATCH  16384
#define NFEAT  50
#define DIM    128
#define NROWS  2000          // feature-table rows (both tables)
#define SLICE_DIMS 16
#define NSLICES 8            // 128 / 16
#define PAD_DW 20            // 16 data dwords + 4 pad -> 80 B/row (b128-aligned, 8 bank-start offsets)
#define COPIES 16
#define ELEMS_PER_COPY (BATCH / COPIES)   // 1024
#define LDS_BYTES (NROWS * PAD_DW * 4)    // 160000 B

// ---------------- Kernel B: feature-sum deltas via LDS-staged table slices ----
// grid = 256 blocks (16 tasks x 16 batch-copies), 1024 threads, 160 KB dynamic LDS.
// task = (table t in {u,i}) x (slice s in 0..7). Block stages rows[0..1999] of
// dims [s*16, s*16+16) into LDS (padded), then for 1024 batch elements gathers
// 50 rows each from LDS and writes the 16-dim partial delta to ws.
__global__ __launch_bounds__(1024) void delta_kernel(
    const int*   __restrict__ ufi,
    const float* __restrict__ ufv,
    const int*   __restrict__ ifi,
    const float* __restrict__ ifv,
    const float* __restrict__ ufe,
    const float* __restrict__ ife,
    float*       __restrict__ dws)     // [2][BATCH][DIM]
{
    extern __shared__ float lds[];

    const int blk  = blockIdx.x;      // 0..255
    const int task = blk >> 4;        // 0..15
    const int copy = blk & 15;        // 0..15
    const int t = task >> 3;          // table: 0=user 1=item
    const int s = task & 7;           // dim slice

    const int*   __restrict__ fi = t ? ifi : ufi;
    const float* __restrict__ fv = t ? ifv : ufv;
    const float* __restrict__ fe = t ? ife : ufe;
    float* __restrict__ dst = dws + (size_t)t * BATCH * DIM;

    const int tid = threadIdx.x;

    // ---- stage slice: 2000 rows x 64 B, coalesced float4 reads ----
    #pragma unroll
    for (int it = 0; it < 8; ++it) {
        int sidx = it * 1024 + tid;            // float4 unit index
        if (sidx < NROWS * 4) {
            int row = sidx >> 2, q2 = sidx & 3;
            float4 vv = *reinterpret_cast<const float4*>(
                fe + (size_t)row * DIM + s * SLICE_DIMS + q2 * 4);
            *reinterpret_cast<float4*>(&lds[row * PAD_DW + q2 * 4]) = vv;
        }
    }
    __syncthreads();

    const int lane = tid & 63;
    const int w    = tid >> 6;        // wave 0..15
    const int q    = lane & 3;        // quad-lane within element
    const int esub = lane >> 2;       // element within wave, 0..15
    const int qoff = q * 4;           // dword offset within row slice

    #pragma unroll
    for (int iter = 0; iter < 4; ++iter) {
        const int e = copy * ELEMS_PER_COPY + iter * 256 + w * 16 + esub;
        const int*   __restrict__ fie = fi + (size_t)e * NFEAT;
        const float* __restrict__ fve = fv + (size_t)e * NFEAT;

        float4 acc = make_float4(0.f, 0.f, 0.f, 0.f);
        #pragma unroll 10
        for (int f = 0; f < NFEAT; ++f) {
            const int   idx = fie[f];          // 4 lanes share the address (broadcast)
            const float val = fve[f];
            const float4 m = *reinterpret_cast<const float4*>(&lds[idx * PAD_DW + qoff]);
            acc.x = fmaf(val, m.x, acc.x);
            acc.y = fmaf(val, m.y, acc.y);
            acc.z = fmaf(val, m.z, acc.z);
            acc.w = fmaf(val, m.w, acc.w);
        }
        *reinterpret_cast<float4*>(dst + (size_t)e * DIM + s * SLICE_DIMS + qoff) = acc;
    }
}

// ---------------- Kernel C: final dot = (u0 + du) . (v0 + dv) -----------------
__global__ __launch_bounds__(256) void final_kernel(
    const int*   __restrict__ user_ids,
    const int*   __restrict__ item_ids,
    const float* __restrict__ user_emb,
    const float* __restrict__ item_emb,
    const float* __restrict__ dws,
    float*       __restrict__ out)
{
    const int tid  = threadIdx.x;
    const int lane = tid & 63;
    const int half = lane >> 5;
    const int sl   = lane & 31;
    const int d0   = sl * 4;

    int wv = (int)((blockIdx.x * blockDim.x + tid) >> 6);
    wv = __builtin_amdgcn_readfirstlane(wv);
    const int b0 = wv * 2, b1 = b0 + 1;
    const int b  = half ? b1 : b0;

    const int uid0 = user_ids[b0], uid1 = user_ids[b1];
    const int iid0 = item_ids[b0], iid1 = item_ids[b1];
    const int ur = half ? uid1 : uid0;
    const int ir = half ? iid1 : iid0;

    const float4 u0 = *reinterpret_cast<const float4*>(user_emb + (size_t)ur * DIM + d0);
    const float4 v0 = *reinterpret_cast<const float4*>(item_emb + (size_t)ir * DIM + d0);
    const float4 du = *reinterpret_cast<const float4*>(dws + (size_t)b * DIM + d0);
    const float4 dv = *reinterpret_cast<const float4*>(dws + (size_t)BATCH * DIM + (size_t)b * DIM + d0);

    float dot = (u0.x + du.x) * (v0.x + dv.x)
              + (u0.y + du.y) * (v0.y + dv.y)
              + (u0.z + du.z) * (v0.z + dv.z)
              + (u0.w + du.w) * (v0.w + dv.w);

    #pragma unroll
    for (int off = 16; off > 0; off >>= 1)
        dot += __shfl_xor(dot, off);

    if (sl == 0) out[b] = dot;
}

// ---------------- Fallback: single-pass R2 kernel (if ws too small) -----------
__global__ __launch_bounds__(256) void mf_dot_fallback(
    const int*   __restrict__ user_ids,
    const int*   __restrict__ item_ids,
    const int*   __restrict__ ufi,
    const float* __restrict__ ufv,
    const int*   __restrict__ ifi,
    const float* __restrict__ ifv,
    const float* __restrict__ user_emb,
    const float* __restrict__ item_emb,
    const float* __restrict__ user_feat_emb,
    const float* __restrict__ item_feat_emb,
    float*       __restrict__ out)
{
    const int tid  = threadIdx.x;
    const int lane = tid & 63;
    const int half = lane >> 5;
    const int sl   = lane & 31;
    const int d0   = sl * 4;

    int wv = (int)((blockIdx.x * blockDim.x + tid) >> 6);
    wv = __builtin_amdgcn_readfirstlane(wv);
    const int b0 = wv * 2, b1 = b0 + 1;
    const int b  = half ? b1 : b0;

    const int uid0 = user_ids[b0], uid1 = user_ids[b1];
    const int iid0 = item_ids[b0], iid1 = item_ids[b1];
    const int urow = half ? uid1 : uid0;
    const int irow = half ? iid1 : iid0;

    float4 uacc = *reinterpret_cast<const float4*>(user_emb + (size_t)urow * DIM + d0);
    float4 vacc = *reinterpret_cast<const float4*>(item_emb + (size_t)irow * DIM + d0);

    const int* __restrict__ ufi0 = ufi + (size_t)b0 * NFEAT;
    const int* __restrict__ ufi1 = ufi + (size_t)b1 * NFEAT;
    const float* __restrict__ ufv0 = ufv + (size_t)b0 * NFEAT;
    const float* __restrict__ ufv1 = ufv + (size_t)b1 * NFEAT;
    const int* __restrict__ ifi0 = ifi + (size_t)b0 * NFEAT;
    const int* __restrict__ ifi1 = ifi + (size_t)b1 * NFEAT;
    const float* __restrict__ ifv0 = ifv + (size_t)b0 * NFEAT;
    const float* __restrict__ ifv1 = ifv + (size_t)b1 * NFEAT;

    #pragma unroll 10
    for (int f = 0; f < NFEAT; ++f) {
        const int   ui0 = ufi0[f], ui1 = ufi1[f];
        const float uv0 = ufv0[f], uv1 = ufv1[f];
        const int   ii0 = ifi0[f], ii1 = ifi1[f];
        const float iv0 = ifv0[f], iv1 = ifv1[f];

        const int   urr = half ? ui1 : ui0;
        const float uw  = half ? uv1 : uv0;
        const int   irr = half ? ii1 : ii0;
        const float iw  = half ? iv1 : iv0;

        const float4 ue = *reinterpret_cast<const float4*>(user_feat_emb + (size_t)urr * DIM + d0);
        const float4 ie = *reinterpret_cast<const float4*>(item_feat_emb + (size_t)irr * DIM + d0);

        uacc.x = fmaf(uw, ue.x, uacc.x);
        uacc.y = fmaf(uw, ue.y, uacc.y);
        uacc.z = fmaf(uw, ue.z, uacc.z);
        uacc.w = fmaf(uw, ue.w, uacc.w);
        vacc.x = fmaf(iw, ie.x, vacc.x);
        vacc.y = fmaf(iw, ie.y, vacc.y);
        vacc.z = fmaf(iw, ie.z, vacc.z);
        vacc.w = fmaf(iw, ie.w, vacc.w);
    }

    float dot = uacc.x * vacc.x + uacc.y * vacc.y + uacc.z * vacc.z + uacc.w * vacc.w;
    #pragma unroll
    for (int off = 16; off > 0; off >>= 1)
        dot += __shfl_xor(dot, off);
    if (sl == 0) out[b] = dot;
}

extern "C" void kernel_launch(void* const* d_in, const int* in_sizes, int n_in,
                              void* d_out, int out_size, void* d_ws, size_t ws_size,
                              hipStream_t stream) {
    const int*   user_ids      = (const int*)  d_in[0];
    const int*   item_ids      = (const int*)  d_in[1];
    const int*   ufi           = (const int*)  d_in[2];
    const float* ufv           = (const float*)d_in[3];
    const int*   ifi           = (const int*)  d_in[4];
    const float* ifv           = (const float*)d_in[5];
    const float* user_emb      = (const float*)d_in[6];
    const float* item_emb      = (const float*)d_in[7];
    const float* user_feat_emb = (const float*)d_in[8];
    const float* item_feat_emb = (const float*)d_in[9];
    float* out = (float*)d_out;

    const size_t ws_needed = (size_t)2 * BATCH * DIM * sizeof(float);  // 16.8 MB

    if (ws_size >= ws_needed) {
        static bool attr_set = false;  // idempotent module attribute; not stream state
        if (!attr_set) {
            hipFuncSetAttribute((const void*)delta_kernel,
                                hipFuncAttributeMaxDynamicSharedMemorySize, LDS_BYTES);
            attr_set = true;
        }
        float* dws = (float*)d_ws;
        delta_kernel<<<COPIES * NSLICES * 2, 1024, LDS_BYTES, stream>>>(
            ufi, ufv, ifi, ifv, user_feat_emb, item_feat_emb, dws);
        final_kernel<<<BATCH / 8, 256, 0, stream>>>(
            user_ids, item_ids, user_emb, item_emb, dws, out);
    } else {
        mf_dot_fallback<<<BATCH / 8, 256, 0, stream>>>(
            user_ids, item_ids, ufi, ufv, ifi, ifv,
            user_emb, item_emb, user_feat_emb, item_feat_emb, out);
    }
}

// Round 4
// 40.867 us; speedup vs baseline: 1.9943x; 1.9943x over previous
//
#include <hip/hip_runtime.h>

#define BATCH  16384
#define NFEAT  50
#define DIM    128
#define NROWS  2000
#define TBL_ELEMS (NROWS * DIM)        // 256000 per table

// ---- Kernel A: convert both feature tables f32 -> bf16 into d_ws ----------
// dst layout: [user_table 256000][item_table 256000] ushorts.
__global__ __launch_bounds__(256) void convert_kernel(
    const float* __restrict__ ufe,
    const float* __restrict__ ife,
    ushort*      __restrict__ dst)
{
    const int i = blockIdx.x * blockDim.x + threadIdx.x;   // one thread = 8 floats
    const int n8 = (2 * TBL_ELEMS) / 8;                    // 64000
    if (i >= n8) return;
    const int base = i * 8;
    const float* src = (base < TBL_ELEMS) ? (ufe + base) : (ife + base - TBL_ELEMS);
    float4 a = *reinterpret_cast<const float4*>(src);
    float4 b = *reinterpret_cast<const float4*>(src + 4);
    uint4 o;
    auto f2bf = [](float x) -> uint {
        uint u = __float_as_uint(x);
        return (u + 0x7fffu + ((u >> 16) & 1u)) >> 16;     // RNE
    };
    o.x = f2bf(a.x) | (f2bf(a.y) << 16);
    o.y = f2bf(a.z) | (f2bf(a.w) << 16);
    o.z = f2bf(b.x) | (f2bf(b.y) << 16);
    o.w = f2bf(b.z) | (f2bf(b.w) << 16);
    *reinterpret_cast<uint4*>(dst + base) = o;
}

// ---- Kernel B: main dot kernel, bf16 feature gathers ----------------------
// One wave = 2 batch elements; 32 lanes/element; lane owns 4 dims.
// Feature rows are bf16 (256 B): lane reads uint2 (8 B) -> 512 B per wave instr.
__global__ __launch_bounds__(256) void mf_dot_bf16(
    const int*   __restrict__ user_ids,
    const int*   __restrict__ item_ids,
    const int*   __restrict__ ufi,
    const float* __restrict__ ufv,
    const int*   __restrict__ ifi,
    const float* __restrict__ ifv,
    const float* __restrict__ user_emb,
    const float* __restrict__ item_emb,
    const ushort* __restrict__ fe_bf,   // [2][2000][128] bf16
    float*       __restrict__ out)
{
    const int tid  = threadIdx.x;
    const int lane = tid & 63;
    const int half = lane >> 5;
    const int sl   = lane & 31;
    const int d0   = sl * 4;

    int wv = (int)((blockIdx.x * blockDim.x + tid) >> 6);
    wv = __builtin_amdgcn_readfirstlane(wv);
    const int b0 = wv * 2, b1 = b0 + 1;
    const int b  = half ? b1 : b0;

    const int uid0 = user_ids[b0], uid1 = user_ids[b1];
    const int iid0 = item_ids[b0], iid1 = item_ids[b1];
    const int urow = half ? uid1 : uid0;
    const int irow = half ? iid1 : iid0;

    float4 uacc = *reinterpret_cast<const float4*>(user_emb + (size_t)urow * DIM + d0);
    float4 vacc = *reinterpret_cast<const float4*>(item_emb + (size_t)irow * DIM + d0);

    const int* __restrict__ ufi0 = ufi + (size_t)b0 * NFEAT;
    const int* __restrict__ ufi1 = ufi + (size_t)b1 * NFEAT;
    const float* __restrict__ ufv0 = ufv + (size_t)b0 * NFEAT;
    const float* __restrict__ ufv1 = ufv + (size_t)b1 * NFEAT;
    const int* __restrict__ ifi0 = ifi + (size_t)b0 * NFEAT;
    const int* __restrict__ ifi1 = ifi + (size_t)b1 * NFEAT;
    const float* __restrict__ ifv0 = ifv + (size_t)b0 * NFEAT;
    const float* __restrict__ ifv1 = ifv + (size_t)b1 * NFEAT;

    const ushort* __restrict__ ufe_bf = fe_bf;
    const ushort* __restrict__ ife_bf = fe_bf + TBL_ELEMS;

    #pragma unroll 10
    for (int f = 0; f < NFEAT; ++f) {
        const int   ui0 = ufi0[f], ui1 = ufi1[f];
        const float uv0 = ufv0[f], uv1 = ufv1[f];
        const int   ii0 = ifi0[f], ii1 = ifi1[f];
        const float iv0 = ifv0[f], iv1 = ifv1[f];

        const int   ur = half ? ui1 : ui0;
        const float uw = half ? uv1 : uv0;
        const int   ir = half ? ii1 : ii0;
        const float iw = half ? iv1 : iv0;

        const uint2 ue = *reinterpret_cast<const uint2*>(ufe_bf + (size_t)ur * DIM + d0);
        const uint2 ie = *reinterpret_cast<const uint2*>(ife_bf + (size_t)ir * DIM + d0);

        uacc.x = fmaf(uw, __uint_as_float(ue.x << 16),          uacc.x);
        uacc.y = fmaf(uw, __uint_as_float(ue.x & 0xffff0000u),  uacc.y);
        uacc.z = fmaf(uw, __uint_as_float(ue.y << 16),          uacc.z);
        uacc.w = fmaf(uw, __uint_as_float(ue.y & 0xffff0000u),  uacc.w);
        vacc.x = fmaf(iw, __uint_as_float(ie.x << 16),          vacc.x);
        vacc.y = fmaf(iw, __uint_as_float(ie.x & 0xffff0000u),  vacc.y);
        vacc.z = fmaf(iw, __uint_as_float(ie.y << 16),          vacc.z);
        vacc.w = fmaf(iw, __uint_as_float(ie.y & 0xffff0000u),  vacc.w);
    }

    float dot = uacc.x * vacc.x + uacc.y * vacc.y + uacc.z * vacc.z + uacc.w * vacc.w;

    #pragma unroll
    for (int off = 16; off > 0; off >>= 1)
        dot += __shfl_xor(dot, off);

    if (sl == 0) out[b] = dot;
}

// ---- Fallback: R2 all-f32 single-pass (if ws too small) -------------------
__global__ __launch_bounds__(256) void mf_dot_fallback(
    const int*   __restrict__ user_ids,
    const int*   __restrict__ item_ids,
    const int*   __restrict__ ufi,
    const float* __restrict__ ufv,
    const int*   __restrict__ ifi,
    const float* __restrict__ ifv,
    const float* __restrict__ user_emb,
    const float* __restrict__ item_emb,
    const float* __restrict__ user_feat_emb,
    const float* __restrict__ item_feat_emb,
    float*       __restrict__ out)
{
    const int tid  = threadIdx.x;
    const int lane = tid & 63;
    const int half = lane >> 5;
    const int sl   = lane & 31;
    const int d0   = sl * 4;

    int wv = (int)((blockIdx.x * blockDim.x + tid) >> 6);
    wv = __builtin_amdgcn_readfirstlane(wv);
    const int b0 = wv * 2, b1 = b0 + 1;
    const int b  = half ? b1 : b0;

    const int uid0 = user_ids[b0], uid1 = user_ids[b1];
    const int iid0 = item_ids[b0], iid1 = item_ids[b1];
    const int urow = half ? uid1 : uid0;
    const int irow = half ? iid1 : iid0;

    float4 uacc = *reinterpret_cast<const float4*>(user_emb + (size_t)urow * DIM + d0);
    float4 vacc = *reinterpret_cast<const float4*>(item_emb + (size_t)irow * DIM + d0);

    #pragma unroll 10
    for (int f = 0; f < NFEAT; ++f) {
        const int   ui0 = ufi[b0 * NFEAT + f], ui1 = ufi[b1 * NFEAT + f];
        const float uv0 = ufv[b0 * NFEAT + f], uv1 = ufv[b1 * NFEAT + f];
        const int   ii0 = ifi[b0 * NFEAT + f], ii1 = ifi[b1 * NFEAT + f];
        const float iv0 = ifv[b0 * NFEAT + f], iv1 = ifv[b1 * NFEAT + f];

        const int   ur = half ? ui1 : ui0;
        const float uw = half ? uv1 : uv0;
        const int   ir = half ? ii1 : ii0;
        const float iw = half ? iv1 : iv0;

        const float4 ue = *reinterpret_cast<const float4*>(user_feat_emb + (size_t)ur * DIM + d0);
        const float4 ie = *reinterpret_cast<const float4*>(item_feat_emb + (size_t)ir * DIM + d0);

        uacc.x = fmaf(uw, ue.x, uacc.x);
        uacc.y = fmaf(uw, ue.y, uacc.y);
        uacc.z = fmaf(uw, ue.z, uacc.z);
        uacc.w = fmaf(uw, ue.w, uacc.w);
        vacc.x = fmaf(iw, ie.x, vacc.x);
        vacc.y = fmaf(iw, ie.y, vacc.y);
        vacc.z = fmaf(iw, ie.z, vacc.z);
        vacc.w = fmaf(iw, ie.w, vacc.w);
    }

    float dot = uacc.x * vacc.x + uacc.y * vacc.y + uacc.z * vacc.z + uacc.w * vacc.w;
    #pragma unroll
    for (int off = 16; off > 0; off >>= 1)
        dot += __shfl_xor(dot, off);
    if (sl == 0) out[b] = dot;
}

extern "C" void kernel_launch(void* const* d_in, const int* in_sizes, int n_in,
                              void* d_out, int out_size, void* d_ws, size_t ws_size,
                              hipStream_t stream) {
    const int*   user_ids      = (const int*)  d_in[0];
    const int*   item_ids      = (const int*)  d_in[1];
    const int*   ufi           = (const int*)  d_in[2];
    const float* ufv           = (const float*)d_in[3];
    const int*   ifi           = (const int*)  d_in[4];
    const float* ifv           = (const float*)d_in[5];
    const float* user_feat_emb = (const float*)d_in[8];
    const float* item_feat_emb = (const float*)d_in[9];
    const float* user_emb      = (const float*)d_in[6];
    const float* item_emb      = (const float*)d_in[7];
    float* out = (float*)d_out;

    const size_t ws_needed = (size_t)2 * TBL_ELEMS * sizeof(ushort);  // ~1 MB

    if (ws_size >= ws_needed) {
        ushort* fe_bf = (ushort*)d_ws;
        const int n8 = (2 * TBL_ELEMS) / 8;                 // 64000 threads
        convert_kernel<<<(n8 + 255) / 256, 256, 0, stream>>>(
            user_feat_emb, item_feat_emb, fe_bf);
        mf_dot_bf16<<<BATCH / 8, 256, 0, stream>>>(
            user_ids, item_ids, ufi, ufv, ifi, ifv,
            user_emb, item_emb, fe_bf, out);
    } else {
        mf_dot_fallback<<<BATCH / 8, 256, 0, stream>>>(
            user_ids, item_ids, ufi, ufv, ifi, ifv,
            user_emb, item_emb, user_feat_emb, item_feat_emb, out);
    }
}